// Round 2
// baseline (400.874 us; speedup 1.0000x reference)
//
#include <hip/hip_runtime.h>

// SpatialTransformer: dense 2D bilinear warp with edge clamping.
// img: [B,C,H,W] fp32, trf: [B,2,H,W] fp32 (ij displacements), out: [B,C,H,W] fp32.
// B=16, C=4, H=W=768.
//
// R3 (= R2 resubmit after container infra failure): two-pass.
// Pass 1 transposes img planar [C,H,W] -> interleaved [H,W,C] (float4/pixel)
// into the workspace — coalesced, BW-bound. Pass 2 gathers ONE float4 per
// bilinear corner (4 divergent loads/pixel instead of 16), attacking the
// address-issue bound seen in R1 (HBM 20%, VALU 12%, occ 81%).

#define BB 16
#define CC 4
#define HH 768
#define WW 768
#define HWSZ (HH * WW)

#define TW 64
#define TH 16
#define RPT 4                      // rows per thread
#define NXT (WW / TW)              // 12 x-tiles
#define NYT (HH / TH)              // 48 y-tiles
#define TILES_PER_B (NXT * NYT)    // 576
#define NTILES (TILES_PER_B * BB)  // 9216
#define NXCD 8

// ---------------- Pass 1: planar -> interleaved ----------------
// Each thread handles 4 consecutive pixels: 4x float4 plane loads (coalesced),
// 4x float4 interleaved stores (the 4-way unroll covers every byte of the
// wave's 4KB output region so L2 merges to full lines).
__global__ __launch_bounds__(256) void interleave_kernel(
    const float* __restrict__ img,
    float4* __restrict__ imgT)
{
    int b = blockIdx.y;
    int p0 = (blockIdx.x * 256 + threadIdx.x) * 4;
    const float* ib = img + (size_t)b * CC * HWSZ;

    float4 v0 = *(const float4*)(ib + 0 * HWSZ + p0);
    float4 v1 = *(const float4*)(ib + 1 * HWSZ + p0);
    float4 v2 = *(const float4*)(ib + 2 * HWSZ + p0);
    float4 v3 = *(const float4*)(ib + 3 * HWSZ + p0);

    float4* ot = imgT + (size_t)b * HWSZ + p0;
    ot[0] = make_float4(v0.x, v1.x, v2.x, v3.x);
    ot[1] = make_float4(v0.y, v1.y, v2.y, v3.y);
    ot[2] = make_float4(v0.z, v1.z, v2.z, v3.z);
    ot[3] = make_float4(v0.w, v1.w, v2.w, v3.w);
}

// ---------------- Pass 2: warp with float4 corner gathers ----------------
__global__ __launch_bounds__(256) void st_warp_gather4(
    const float4* __restrict__ imgT,
    const float* __restrict__ trf,
    float* __restrict__ out)
{
    // XCD-aware swizzle: block l lands on XCD l%8; each XCD streams a
    // contiguous run of tiles (ht fastest) -> vertical halo reuse in its L2.
    int l = blockIdx.x;
    int xcd = l & (NXCD - 1);
    int t = xcd * (NTILES / NXCD) + (l >> 3);
    int b = t / TILES_PER_B;
    int rem = t - b * TILES_PER_B;
    int wt = rem / NYT;
    int ht = rem - wt * NYT;

    int tx = threadIdx.x & 63;          // one wave = one row: coalesced
    int ty = threadIdx.x >> 6;          // 0..3
    int w = wt * TW + tx;
    int h_base = ht * TH + ty * RPT;

    const float maxy = (float)(HH - 1);
    const float maxx = (float)(WW - 1);

    const float* tb = trf + (size_t)b * 2 * HWSZ;
    const float4* it = imgT + (size_t)b * HWSZ;
    float* ob = out + (size_t)b * CC * HWSZ;

#pragma unroll
    for (int r = 0; r < RPT; ++r) {
        int h = h_base + r;
        int p = h * WW + w;

        float dy = __builtin_nontemporal_load(tb + p);
        float dx = __builtin_nontemporal_load(tb + p + HWSZ);

        float y = (float)h + dy;
        float x = (float)w + dx;

        float cy = fminf(fmaxf(y, 0.0f), maxy);
        float cx = fminf(fmaxf(x, 0.0f), maxx);

        float f0y = fminf(fmaxf(floorf(y), 0.0f), maxy);
        float f0x = fminf(fmaxf(floorf(x), 0.0f), maxx);
        float f1y = fminf(f0y + 1.0f, maxy);
        float f1x = fminf(f0x + 1.0f, maxx);

        // neurite convention: weight of floor corner = loc1 - clipped
        float wy0 = f1y - cy;
        float wx0 = f1x - cx;
        float wy1 = 1.0f - wy0;
        float wx1 = 1.0f - wx0;

        int i0y = (int)f0y;
        int i0x = (int)f0x;
        int i1y = (int)f1y;
        int i1x = (int)f1x;

        float4 c00 = it[i0y * WW + i0x];
        float4 c01 = it[i0y * WW + i1x];
        float4 c10 = it[i1y * WW + i0x];
        float4 c11 = it[i1y * WW + i1x];

        float w00 = wy0 * wx0;
        float w01 = wy0 * wx1;
        float w10 = wy1 * wx0;
        float w11 = wy1 * wx1;

        float4 v;
        v.x = w00 * c00.x + w01 * c01.x + w10 * c10.x + w11 * c11.x;
        v.y = w00 * c00.y + w01 * c01.y + w10 * c10.y + w11 * c11.y;
        v.z = w00 * c00.z + w01 * c01.z + w10 * c10.z + w11 * c11.z;
        v.w = w00 * c00.w + w01 * c01.w + w10 * c10.w + w11 * c11.w;

        __builtin_nontemporal_store(v.x, ob + 0 * HWSZ + p);
        __builtin_nontemporal_store(v.y, ob + 1 * HWSZ + p);
        __builtin_nontemporal_store(v.z, ob + 2 * HWSZ + p);
        __builtin_nontemporal_store(v.w, ob + 3 * HWSZ + p);
    }
}

// ---------------- Fallback (R1 kernel): used if workspace too small ----------------
__global__ __launch_bounds__(256) void st_warp_kernel(
    const float* __restrict__ img,
    const float* __restrict__ trf,
    float* __restrict__ out)
{
    int l = blockIdx.x;
    int xcd = l & (NXCD - 1);
    int t = xcd * (NTILES / NXCD) + (l >> 3);
    int b = t / TILES_PER_B;
    int rem = t - b * TILES_PER_B;
    int wt = rem / NYT;
    int ht = rem - wt * NYT;

    int tx = threadIdx.x & 63;
    int ty = threadIdx.x >> 6;
    int w = wt * TW + tx;
    int h_base = ht * TH + ty * RPT;

    const float maxy = (float)(HH - 1);
    const float maxx = (float)(WW - 1);

    const float* tb = trf + (size_t)b * 2 * HWSZ;
    const float* ib = img + (size_t)b * CC * HWSZ;
    float* ob = out + (size_t)b * CC * HWSZ;

#pragma unroll
    for (int r = 0; r < RPT; ++r) {
        int h = h_base + r;
        int p = h * WW + w;

        float dy = __builtin_nontemporal_load(tb + p);
        float dx = __builtin_nontemporal_load(tb + p + HWSZ);

        float y = (float)h + dy;
        float x = (float)w + dx;

        float cy = fminf(fmaxf(y, 0.0f), maxy);
        float cx = fminf(fmaxf(x, 0.0f), maxx);

        float f0y = fminf(fmaxf(floorf(y), 0.0f), maxy);
        float f0x = fminf(fmaxf(floorf(x), 0.0f), maxx);
        float f1y = fminf(f0y + 1.0f, maxy);
        float f1x = fminf(f0x + 1.0f, maxx);

        float wy0 = f1y - cy;
        float wx0 = f1x - cx;
        float wy1 = 1.0f - wy0;
        float wx1 = 1.0f - wx0;

        int i0y = (int)f0y;
        int i0x = (int)f0x;
        int i1y = (int)f1y;
        int i1x = (int)f1x;

        int o00 = i0y * WW + i0x;
        int o01 = i0y * WW + i1x;
        int o10 = i1y * WW + i0x;
        int o11 = i1y * WW + i1x;

        float w00 = wy0 * wx0;
        float w01 = wy0 * wx1;
        float w10 = wy1 * wx0;
        float w11 = wy1 * wx1;

#pragma unroll
        for (int c = 0; c < CC; ++c) {
            const float* ic = ib + c * HWSZ;
            float v = w00 * ic[o00] + w01 * ic[o01]
                    + w10 * ic[o10] + w11 * ic[o11];
            __builtin_nontemporal_store(v, ob + c * HWSZ + p);
        }
    }
}

extern "C" void kernel_launch(void* const* d_in, const int* in_sizes, int n_in,
                              void* d_out, int out_size, void* d_ws, size_t ws_size,
                              hipStream_t stream) {
    const float* img = (const float*)d_in[0];
    const float* trf = (const float*)d_in[1];
    float* out = (float*)d_out;

    const size_t need = (size_t)BB * HWSZ * sizeof(float4);  // ~151 MB interleaved copy
    if (d_ws != nullptr && ws_size >= need) {
        float4* imgT = (float4*)d_ws;
        // HWSZ / (256 threads * 4 px) = 576 blocks per batch image
        interleave_kernel<<<dim3(HWSZ / (256 * 4), BB), 256, 0, stream>>>(img, imgT);
        st_warp_gather4<<<NTILES, 256, 0, stream>>>(imgT, trf, out);
    } else {
        st_warp_kernel<<<NTILES, 256, 0, stream>>>(img, trf, out);
    }
}

// Round 3
// 313.751 us; speedup vs baseline: 1.2777x; 1.2777x over previous
//
#include <hip/hip_runtime.h>

// SpatialTransformer: dense 2D bilinear warp with edge clamping.
// img: [B,C,H,W] fp32, trf: [B,2,H,W] fp32 (ij displacements), out: [B,C,H,W] fp32.
// B=16, C=4, H=W=768.
//
// R4: single fused kernel. Each block stages its 64x32 output tile + 8px halo
// of img (4 channels interleaved -> float4) into LDS with COALESCED planar
// reads, then bilinear gathers hit LDS (ds_read_b128, lane-consecutive ->
// conflict-free). disp ~ N(0,1) so the 8px halo covers all samples on these
// inputs (max|disp|~5.8 over 19M draws); a per-pixel global fallback keeps
// correctness for arbitrary displacements. Kills R3's 302MB transpose
// round-trip AND converts divergent gathers into LDS reads: the kernel's
// global traffic is 100% coalesced streams (img-tile reads, trf, out).

typedef float fvec4 __attribute__((ext_vector_type(4)));

#define BB 16
#define CC 4
#define HH 768
#define WW 768
#define HWSZ (HH * WW)

#define TW 64
#define TH 32
#define HALO 8
#define TLW (TW + 2 * HALO)          // 80
#define TLH (TH + 2 * HALO)          // 48
#define TILE_PX (TLH * TLW)          // 3840 staged pixels (60 KB as float4)
#define NXT (WW / TW)                // 12
#define NYT (HH / TH)                // 24
#define TILES_PER_B (NXT * NYT)      // 288
#define NTILES (TILES_PER_B * BB)    // 4608
#define NXCD 8
#define NTHR 512                     // 8 waves: wave w owns rows 4w..4w+3
#define RPT 4                        // rows per thread

__global__ __launch_bounds__(NTHR) void st_warp_lds(
    const float* __restrict__ img,
    const float* __restrict__ trf,
    float* __restrict__ out)
{
    __shared__ fvec4 tile[TILE_PX];  // 61440 B -> 2 blocks/CU

    // XCD-aware swizzle: block l -> XCD l%8; each XCD walks ht fastest down a
    // 64-wide column band so vertically-adjacent tiles' halos overlap in L2.
    int l = blockIdx.x;
    int xcd = l & (NXCD - 1);
    int t = xcd * (NTILES / NXCD) + (l >> 3);
    int b = t / TILES_PER_B;
    int rem = t - b * TILES_PER_B;
    int wt = rem / NYT;
    int ht = rem - wt * NYT;
    int h0 = ht * TH, w0 = wt * TW;
    int oy = h0 - HALO, ox = w0 - HALO;  // staged-tile origin (may be <0; staged clamped)

    const float* ib = img + (size_t)b * CC * HWSZ;
    const float* tb = trf + (size_t)b * 2 * HWSZ;
    float* ob = out + (size_t)b * CC * HWSZ;

    int tid = threadIdx.x;
    int lane = tid & 63;            // one wave = one 64-wide row: coalesced
    int wv = tid >> 6;              // 0..7
    int hbase = h0 + wv * RPT;
    int w = w0 + lane;

    // Issue trf loads FIRST: their latency hides under the staging phase.
    float dys[RPT], dxs[RPT];
#pragma unroll
    for (int r = 0; r < RPT; ++r) {
        int p = (hbase + r) * WW + w;
        dys[r] = __builtin_nontemporal_load(tb + p);
        dxs[r] = __builtin_nontemporal_load(tb + p + HWSZ);
    }

    // Stage img tile+halo: planar -> interleaved float4, edge-clamped.
    // Consecutive threads read consecutive pixels within a channel plane
    // (coalesced); ds_write_b128 at stride-16B (conflict-free).
#pragma unroll
    for (int i = 0; i < (TILE_PX + NTHR - 1) / NTHR; ++i) {
        int s = tid + i * NTHR;
        if (s < TILE_PX) {
            int ly = s / TLW;
            int lx = s - ly * TLW;
            int gy = min(max(oy + ly, 0), HH - 1);
            int gx = min(max(ox + lx, 0), WW - 1);
            int gp = gy * WW + gx;
            fvec4 px = { ib[gp], ib[gp + HWSZ], ib[gp + 2 * HWSZ], ib[gp + 3 * HWSZ] };
            tile[s] = px;
        }
    }
    __syncthreads();

    const float maxy = (float)(HH - 1);
    const float maxx = (float)(WW - 1);

#pragma unroll
    for (int r = 0; r < RPT; ++r) {
        int h = hbase + r;
        int p = h * WW + w;

        float y = (float)h + dys[r];
        float x = (float)w + dxs[r];

        float cy = fminf(fmaxf(y, 0.0f), maxy);
        float cx = fminf(fmaxf(x, 0.0f), maxx);

        float f0y = fminf(fmaxf(floorf(y), 0.0f), maxy);
        float f0x = fminf(fmaxf(floorf(x), 0.0f), maxx);
        float f1y = fminf(f0y + 1.0f, maxy);
        float f1x = fminf(f0x + 1.0f, maxx);

        // neurite convention: weight of floor corner = loc1 - clipped
        float wy0 = f1y - cy;
        float wx0 = f1x - cx;
        float wy1 = 1.0f - wy0;
        float wx1 = 1.0f - wx0;

        int i0y = (int)f0y;
        int i0x = (int)f0x;
        int i1y = (int)f1y;
        int i1x = (int)f1x;

        float w00 = wy0 * wx0;
        float w01 = wy0 * wx1;
        float w10 = wy1 * wx0;
        float w11 = wy1 * wx1;

        fvec4 v;
        if (i0y >= oy && i1y <= oy + TLH - 1 && i0x >= ox && i1x <= ox + TLW - 1) {
            // In staged tile (always true for |disp| <= HALO). Lane-consecutive
            // ds_read_b128: 16-lane phase spans 256B = all 32 banks once.
            int l0 = (i0y - oy) * TLW - ox;
            int l1 = (i1y - oy) * TLW - ox;
            fvec4 c00 = tile[l0 + i0x];
            fvec4 c01 = tile[l0 + i1x];
            fvec4 c10 = tile[l1 + i0x];
            fvec4 c11 = tile[l1 + i1x];
            v = w00 * c00 + w01 * c01 + w10 * c10 + w11 * c11;
        } else {
            // Rare (never on N(0,1) inputs): global planar gather fallback.
            int o00 = i0y * WW + i0x;
            int o01 = i0y * WW + i1x;
            int o10 = i1y * WW + i0x;
            int o11 = i1y * WW + i1x;
#pragma unroll
            for (int c = 0; c < CC; ++c) {
                const float* ic = ib + c * HWSZ;
                v[c] = w00 * ic[o00] + w01 * ic[o01]
                     + w10 * ic[o10] + w11 * ic[o11];
            }
        }

        // Planar stores: wave writes 256B/channel/row — full-line coalesced.
        __builtin_nontemporal_store(v.x, ob + 0 * HWSZ + p);
        __builtin_nontemporal_store(v.y, ob + 1 * HWSZ + p);
        __builtin_nontemporal_store(v.z, ob + 2 * HWSZ + p);
        __builtin_nontemporal_store(v.w, ob + 3 * HWSZ + p);
    }
}

extern "C" void kernel_launch(void* const* d_in, const int* in_sizes, int n_in,
                              void* d_out, int out_size, void* d_ws, size_t ws_size,
                              hipStream_t stream) {
    const float* img = (const float*)d_in[0];
    const float* trf = (const float*)d_in[1];
    float* out = (float*)d_out;

    st_warp_lds<<<NTILES, NTHR, 0, stream>>>(img, trf, out);
}